// Round 1
// baseline (1953.804 us; speedup 1.0000x reference)
//
#include <hip/hip_runtime.h>

#define N_NODES_C 100000
#define N_GRAPHS_C 128

// ---------------- CSR build ----------------
__global__ void hist_kernel(const int* __restrict__ ei, int E, int* __restrict__ deg) {
    int i = blockIdx.x * blockDim.x + threadIdx.x;
    if (i < E) atomicAdd(&deg[ei[E + i]], 1);   // dst row of edge_index
}

__global__ void scan1_kernel(const int* __restrict__ deg, int N,
                             int* __restrict__ tmp, int* __restrict__ bsum) {
    __shared__ int sh[512];
    int t = threadIdx.x;
    int i = blockIdx.x * 512 + t;
    int v = (i < N) ? deg[i] : 0;
    sh[t] = v;
    __syncthreads();
    for (int off = 1; off < 512; off <<= 1) {
        int add = (t >= off) ? sh[t - off] : 0;
        __syncthreads();
        sh[t] += add;
        __syncthreads();
    }
    if (i < N) tmp[i] = sh[t] - v;          // exclusive within block
    if (t == 511) bsum[blockIdx.x] = sh[511];
}

__global__ void scan2_kernel(int* bsum, int nb) {
    if (threadIdx.x == 0 && blockIdx.x == 0) {
        int run = 0;
        for (int j = 0; j < nb; ++j) { int v = bsum[j]; bsum[j] = run; run += v; }
    }
}

__global__ void scan3_kernel(const int* __restrict__ tmp, const int* __restrict__ bsum,
                             int N, int* __restrict__ rowp) {
    int i = blockIdx.x * 512 + threadIdx.x;
    if (i < N) rowp[i] = tmp[i] + bsum[blockIdx.x];
}

__global__ void fill_kernel(const int* __restrict__ ei, int E, const int* __restrict__ rowp,
                            int* __restrict__ cursor, int* __restrict__ csr) {
    int i = blockIdx.x * blockDim.x + threadIdx.x;
    if (i < E) {
        int d = ei[E + i];
        int pos = rowp[d] + atomicAdd(&cursor[d], 1);
        csr[pos] = ei[i];                    // src row
    }
}

// ---------------- neighbor aggregation (gather, wave per node) ----------------
template <int FIN>
__global__ __launch_bounds__(256) void agg_kernel(const float* __restrict__ xin,
                                                  const int* __restrict__ rowp,
                                                  const int* __restrict__ degv,
                                                  const int* __restrict__ csrc,
                                                  float* __restrict__ aggout, int nNodes) {
    int wave = blockIdx.x * (blockDim.x >> 6) + (threadIdx.x >> 6);
    int lane = threadIdx.x & 63;
    if (wave >= nNodes) return;
    int n = wave;
    int start = rowp[n];
    int deg = degv[n];
    float accx = 0.f, accy = 0.f;
    for (int base = 0; base < deg; base += 64) {
        int cnt = min(64, deg - base);
        int sid = (lane < cnt) ? csrc[start + base + lane] : 0;
        for (int j = 0; j < cnt; ++j) {
            int s = __shfl(sid, j);
            if (FIN == 64) {
                accx += xin[s * 64 + lane];
            } else {
                float2 v = ((const float2*)xin)[s * 64 + lane];
                accx += v.x; accy += v.y;
            }
        }
    }
    if (FIN == 64) {
        aggout[n * 64 + lane] = accx;
    } else {
        float2 o; o.x = accx; o.y = accy;
        ((float2*)aggout)[n * 64 + lane] = o;
    }
}

// ---------------- fused dual-GEMM transform ----------------
// h_out[n][o] = act( b[o] + sum_k Wrel[o][k]*agg[n][k] + sum_k Wroot[o][k]*xin[n][k] )
// block: 256 thr; 64-node tile (tx) x 64-output half (blockIdx.y), 16 outputs/thread (ty)
__device__ __forceinline__ int wcol(int oo, int k) {
    return (((((oo >> 2) ^ k) & 15)) << 2) | (oo & 3);   // 4-aligned XOR swizzle
}

template <int FIN, bool RELU>
__global__ __launch_bounds__(256) void transform_kernel(
    const float* __restrict__ agg, const float* __restrict__ xin,
    const float* __restrict__ Wrel, const float* __restrict__ Wroot,
    const float* __restrict__ bias, float* __restrict__ hout, int nNodes) {
    __shared__ float wr[FIN][64];
    __shared__ float wo[FIN][64];
    __shared__ float Aa[64][32];
    __shared__ float Ax[64][32];
    int t = threadIdx.x;
    int half = blockIdx.y;

    for (int idx = t; idx < 64 * FIN; idx += 256) {
        int oo = idx / FIN, k = idx % FIN;
        int c = wcol(oo, k);
        wr[k][c] = Wrel[(half * 64 + oo) * FIN + k];
        wo[k][c] = Wroot[(half * 64 + oo) * FIN + k];
    }

    int tx = t & 63, ty = t >> 6;
    int n = blockIdx.x * 64 + tx;
    bool valid = n < nNodes;
    float acc[16];
#pragma unroll
    for (int i = 0; i < 16; ++i) acc[i] = 0.f;

#pragma unroll 1
    for (int kc = 0; kc < FIN; kc += 32) {
        __syncthreads();   // protects weight stage (1st iter) + prev-chunk reads
        for (int idx = t; idx < 64 * 32; idx += 256) {
            int r = idx >> 5, c = idx & 31;
            int cs = c ^ (r & 31);
            int nn = blockIdx.x * 64 + r;
            float va = 0.f, vx = 0.f;
            if (nn < nNodes) {
                va = agg[nn * FIN + kc + c];
                vx = xin[nn * FIN + kc + c];
            }
            Aa[r][cs] = va;
            Ax[r][cs] = vx;
        }
        __syncthreads();
#pragma unroll 8
        for (int c = 0; c < 32; ++c) {
            int k = kc + c;
            float a  = Aa[tx][c ^ (tx & 31)];
            float xr = Ax[tx][c ^ (tx & 31)];
#pragma unroll
            for (int j = 0; j < 4; ++j) {
                int col = wcol(ty * 16 + j * 4, k);
                float4 w4 = *(const float4*)&wr[k][col];
                float4 v4 = *(const float4*)&wo[k][col];
                acc[j * 4 + 0] += w4.x * a + v4.x * xr;
                acc[j * 4 + 1] += w4.y * a + v4.y * xr;
                acc[j * 4 + 2] += w4.z * a + v4.z * xr;
                acc[j * 4 + 3] += w4.w * a + v4.w * xr;
            }
        }
    }

    if (valid) {
        int ob = half * 64 + ty * 16;
#pragma unroll
        for (int i = 0; i < 16; ++i) {
            float v = acc[i] + bias[ob + i];
            if (RELU) v = fmaxf(v, 0.f);
            hout[n * 128 + ob + i] = v;
        }
    }
}

// ---------------- pooling ----------------
__global__ void cnt_kernel(const int* __restrict__ batch, int N, int* __restrict__ cnt) {
    int i = blockIdx.x * blockDim.x + threadIdx.x;
    if (i < N) atomicAdd(&cnt[batch[i]], 1);
}

__global__ void pool_kernel(const float* __restrict__ h, const int* __restrict__ batch,
                            float* __restrict__ pool, int nNodes) {
    int f = threadIdx.x & 127;
    int sub = threadIdx.x >> 7;
    int startn = blockIdx.x * 128;
    int endn = min(startn + 128, nNodes);
    float local = 0.f;
    int cur = -1;
    for (int n = startn + sub; n < endn; n += 2) {
        int g = batch[n];
        if (g != cur) {
            if (cur >= 0) atomicAdd(&pool[cur * 128 + f], local);
            cur = g; local = 0.f;
        }
        local += h[n * 128 + f];
    }
    if (cur >= 0) atomicAdd(&pool[cur * 128 + f], local);
}

__global__ void final_kernel(const float* __restrict__ pool, const int* __restrict__ cnt,
                             const float* __restrict__ Wlin, const float* __restrict__ blin,
                             float* __restrict__ out) {
    int idx = blockIdx.x * blockDim.x + threadIdx.x;   // 2048 = 128 graphs x 16 classes
    int g = idx >> 4, c = idx & 15;
    float s = 0.f;
    for (int k = 0; k < 128; ++k) s += pool[g * 128 + k] * Wlin[c * 128 + k];
    float inv = 1.0f / fmaxf((float)cnt[g], 1.0f);
    out[idx] = s * inv + blin[c];
}

// ---------------- launch ----------------
extern "C" void kernel_launch(void* const* d_in, const int* in_sizes, int n_in,
                              void* d_out, int out_size, void* d_ws, size_t ws_size,
                              hipStream_t stream) {
    const float* x      = (const float*)d_in[0];
    const int*   ei     = (const int*)d_in[1];
    const int*   batch  = (const int*)d_in[2];
    const float* W1_rel = (const float*)d_in[3];
    const float* b1     = (const float*)d_in[4];
    const float* W1_root= (const float*)d_in[5];
    const float* W2_rel = (const float*)d_in[6];
    const float* b2     = (const float*)d_in[7];
    const float* W2_root= (const float*)d_in[8];
    const float* W3_rel = (const float*)d_in[9];
    const float* b3     = (const float*)d_in[10];
    const float* W3_root= (const float*)d_in[11];
    const float* W_lin  = (const float*)d_in[12];
    const float* b_lin  = (const float*)d_in[13];
    float* out = (float*)d_out;

    const int N = in_sizes[2];          // 100000
    const int E = in_sizes[1] / 2;      // 1600000
    const int nb = (N + 511) / 512;

    // workspace carve-up (256B aligned)
    char* base = (char*)d_ws;
    size_t off = 0;
    auto carve = [&](size_t bytes) -> void* {
        void* p = base + off;
        off = (off + bytes + 255) & ~(size_t)255;
        return p;
    };
    int*   deg    = (int*)carve((size_t)N * 4);
    int*   tmp    = (int*)carve((size_t)N * 4);
    int*   bsum   = (int*)carve(1024);
    int*   rowp   = (int*)carve((size_t)(N + 1) * 4);
    int*   cursor = (int*)carve((size_t)N * 4);
    int*   csr    = (int*)carve((size_t)E * 4);
    float* aggbuf = (float*)carve((size_t)N * 128 * 4);
    float* hA     = (float*)carve((size_t)N * 128 * 4);
    float* hB     = (float*)carve((size_t)N * 128 * 4);
    float* pool   = (float*)carve((size_t)N_GRAPHS_C * 128 * 4);
    int*   gcnt   = (int*)carve((size_t)N_GRAPHS_C * 4);
    (void)ws_size;

    hipMemsetAsync(deg, 0, (size_t)N * 4, stream);
    hipMemsetAsync(cursor, 0, (size_t)N * 4, stream);
    hipMemsetAsync(pool, 0, (size_t)N_GRAPHS_C * 128 * 4, stream);
    hipMemsetAsync(gcnt, 0, (size_t)N_GRAPHS_C * 4, stream);

    // CSR build
    hist_kernel<<<(E + 255) / 256, 256, 0, stream>>>(ei, E, deg);
    scan1_kernel<<<nb, 512, 0, stream>>>(deg, N, tmp, bsum);
    scan2_kernel<<<1, 64, 0, stream>>>(bsum, nb);
    scan3_kernel<<<nb, 512, 0, stream>>>(tmp, bsum, N, rowp);
    fill_kernel<<<(E + 255) / 256, 256, 0, stream>>>(ei, E, rowp, cursor, csr);

    const int aggGrid = (N + 3) / 4;         // 4 waves/block, wave per node
    const int tGridX = (N + 63) / 64;

    // layer 1 (FIN=64)
    agg_kernel<64><<<aggGrid, 256, 0, stream>>>(x, rowp, deg, csr, aggbuf, N);
    transform_kernel<64, true><<<dim3(tGridX, 2), 256, 0, stream>>>(
        aggbuf, x, W1_rel, W1_root, b1, hA, N);

    // layer 2 (FIN=128)
    agg_kernel<128><<<aggGrid, 256, 0, stream>>>(hA, rowp, deg, csr, aggbuf, N);
    transform_kernel<128, true><<<dim3(tGridX, 2), 256, 0, stream>>>(
        aggbuf, hA, W2_rel, W2_root, b2, hB, N);

    // layer 3 (FIN=128, no relu)
    agg_kernel<128><<<aggGrid, 256, 0, stream>>>(hB, rowp, deg, csr, aggbuf, N);
    transform_kernel<128, false><<<dim3(tGridX, 2), 256, 0, stream>>>(
        aggbuf, hB, W3_rel, W3_root, b3, hA, N);

    // pooling + classifier
    cnt_kernel<<<(N + 255) / 256, 256, 0, stream>>>(batch, N, gcnt);
    pool_kernel<<<(N + 127) / 128, 256, 0, stream>>>(hA, batch, pool, N);
    final_kernel<<<8, 256, 0, stream>>>(pool, gcnt, W_lin, b_lin, out);
}

// Round 2
// 1223.963 us; speedup vs baseline: 1.5963x; 1.5963x over previous
//
#include <hip/hip_runtime.h>

#define N_NODES_C 100000
#define N_GRAPHS_C 128

// ---------------- CSR build ----------------
__global__ void hist_kernel(const int* __restrict__ ei, int E, int* __restrict__ deg) {
    int i = blockIdx.x * blockDim.x + threadIdx.x;
    if (i < E) atomicAdd(&deg[ei[E + i]], 1);   // dst row of edge_index
}

__global__ void scan1_kernel(const int* __restrict__ deg, int N,
                             int* __restrict__ tmp, int* __restrict__ bsum) {
    __shared__ int sh[512];
    int t = threadIdx.x;
    int i = blockIdx.x * 512 + t;
    int v = (i < N) ? deg[i] : 0;
    sh[t] = v;
    __syncthreads();
    for (int off = 1; off < 512; off <<= 1) {
        int add = (t >= off) ? sh[t - off] : 0;
        __syncthreads();
        sh[t] += add;
        __syncthreads();
    }
    if (i < N) tmp[i] = sh[t] - v;          // exclusive within block
    if (t == 511) bsum[blockIdx.x] = sh[511];
}

__global__ void scan2_kernel(int* bsum, int nb) {
    if (threadIdx.x == 0 && blockIdx.x == 0) {
        int run = 0;
        for (int j = 0; j < nb; ++j) { int v = bsum[j]; bsum[j] = run; run += v; }
    }
}

__global__ void scan3_kernel(const int* __restrict__ tmp, const int* __restrict__ bsum,
                             int N, int* __restrict__ rowp) {
    int i = blockIdx.x * 512 + threadIdx.x;
    if (i < N) rowp[i] = tmp[i] + bsum[blockIdx.x];
}

__global__ void fill_kernel(const int* __restrict__ ei, int E, const int* __restrict__ rowp,
                            int* __restrict__ cursor, int* __restrict__ csr) {
    int i = blockIdx.x * blockDim.x + threadIdx.x;
    if (i < E) {
        int d = ei[E + i];
        int pos = rowp[d] + atomicAdd(&cursor[d], 1);
        csr[pos] = ei[i];                    // src row
    }
}

// ---------------- neighbor aggregation (gather, wave per node) ----------------
template <int FIN>
__global__ __launch_bounds__(256) void agg_kernel(const float* __restrict__ xin,
                                                  const int* __restrict__ rowp,
                                                  const int* __restrict__ degv,
                                                  const int* __restrict__ csrc,
                                                  float* __restrict__ aggout, int nNodes) {
    int wave = blockIdx.x * (blockDim.x >> 6) + (threadIdx.x >> 6);
    int lane = threadIdx.x & 63;
    if (wave >= nNodes) return;
    int n = wave;
    int start = rowp[n];
    int deg = degv[n];
    float accx = 0.f, accy = 0.f;
    for (int base = 0; base < deg; base += 64) {
        int cnt = min(64, deg - base);
        int sid = (lane < cnt) ? csrc[start + base + lane] : 0;
        for (int j = 0; j < cnt; ++j) {
            int s = __shfl(sid, j);
            if (FIN == 64) {
                accx += xin[s * 64 + lane];
            } else {
                float2 v = ((const float2*)xin)[s * 64 + lane];
                accx += v.x; accy += v.y;
            }
        }
    }
    if (FIN == 64) {
        aggout[n * 64 + lane] = accx;
    } else {
        float2 o; o.x = accx; o.y = accy;
        ((float2*)aggout)[n * 64 + lane] = o;
    }
}

// ---------------- fused dual-GEMM transform (register-tiled) ----------------
// C[N x 128] = [agg | x] (N x KTOT) * [Wrel ; Wroot]^T (KTOT x 128) + bias, opt. ReLU
// block: 256 thr, tile 128 nodes x 128 outs; thread: 8 nodes x 8 outs register tile.
// LDS: sA[16][128] (k-major, transposed A chunk), sW[16][128]. 16 KB total.
template <int KTOT, bool RELU>
__global__ __launch_bounds__(256) void xform_kernel(
    const float* __restrict__ agg, const float* __restrict__ xin,
    const float* __restrict__ Wrel, const float* __restrict__ Wroot,
    const float* __restrict__ bias, float* __restrict__ hout, int nNodes)
{
    constexpr int KH = KTOT / 2;           // per-matrix K (64 or 128)
    __shared__ float sA[16][128];
    __shared__ float sW[16][128];
    const int t  = threadIdx.x;
    const int nb0 = blockIdx.x * 128;
    const int tx = t & 15;                 // node group: nodes tx*4..+3 and 64+tx*4..+3
    const int ty = t >> 4;                 // out group:  outs  ty*4..+3 and 64+ty*4..+3
    const int ln = t & 127;                // staging lane: node/out index within tile
    const int lj = t >> 7;                 // staging: which float4-column (0/1; +2 for 2nd)

    float acc[8][8];
#pragma unroll
    for (int r = 0; r < 8; ++r)
#pragma unroll
        for (int c = 0; c < 8; ++c) acc[r][c] = 0.f;

    const int gn = nb0 + ln;
    const bool gvalid = gn < nNodes;
    const size_t arow = (size_t)gn * KH;

    float4 va[2], vw[2];
    // prefetch chunk 0
    {
        const float* srcA = agg; const float* srcW = Wrel;
#pragma unroll
        for (int q = 0; q < 2; ++q) {
            int j = lj + q * 2;
            va[q] = gvalid ? *(const float4*)&srcA[arow + j * 4]
                           : make_float4(0.f, 0.f, 0.f, 0.f);
            vw[q] = *(const float4*)&srcW[(size_t)ln * KH + j * 4];
        }
    }

    constexpr int NC = KTOT / 16;          // chunks
#pragma unroll 1
    for (int cix = 0; cix < NC; ++cix) {
        __syncthreads();                   // previous chunk fully consumed
#pragma unroll
        for (int q = 0; q < 2; ++q) {
            int j = lj + q * 2;
            sA[j * 4 + 0][ln] = va[q].x; sA[j * 4 + 1][ln] = va[q].y;
            sA[j * 4 + 2][ln] = va[q].z; sA[j * 4 + 3][ln] = va[q].w;
            sW[j * 4 + 0][ln] = vw[q].x; sW[j * 4 + 1][ln] = vw[q].y;
            sW[j * 4 + 2][ln] = vw[q].z; sW[j * 4 + 3][ln] = vw[q].w;
        }
        __syncthreads();

        // prefetch next chunk while computing this one
        if (cix + 1 < NC) {
            int kc = (cix + 1) * 16;
            const float* srcA = (kc < KH) ? agg : xin;
            const float* srcW = (kc < KH) ? Wrel : Wroot;
            int kof = (kc < KH) ? kc : kc - KH;
#pragma unroll
            for (int q = 0; q < 2; ++q) {
                int j = lj + q * 2;
                va[q] = gvalid ? *(const float4*)&srcA[arow + kof + j * 4]
                               : make_float4(0.f, 0.f, 0.f, 0.f);
                vw[q] = *(const float4*)&srcW[(size_t)ln * KH + kof + j * 4];
            }
        }

#pragma unroll
        for (int i = 0; i < 16; ++i) {
            float4 a0 = *(const float4*)&sA[i][tx * 4];
            float4 a1 = *(const float4*)&sA[i][64 + tx * 4];
            float4 w0 = *(const float4*)&sW[i][ty * 4];
            float4 w1 = *(const float4*)&sW[i][64 + ty * 4];
            float av[8] = {a0.x, a0.y, a0.z, a0.w, a1.x, a1.y, a1.z, a1.w};
            float wv[8] = {w0.x, w0.y, w0.z, w0.w, w1.x, w1.y, w1.z, w1.w};
#pragma unroll
            for (int r = 0; r < 8; ++r)
#pragma unroll
                for (int c = 0; c < 8; ++c)
                    acc[r][c] += av[r] * wv[c];
        }
    }

    // epilogue
    float4 b0 = *(const float4*)&bias[ty * 4];
    float4 b1 = *(const float4*)&bias[64 + ty * 4];
    float bv[8] = {b0.x, b0.y, b0.z, b0.w, b1.x, b1.y, b1.z, b1.w};
#pragma unroll
    for (int r = 0; r < 8; ++r) {
        int n = nb0 + ((r < 4) ? (tx * 4 + r) : (64 + tx * 4 + (r - 4)));
        if (n >= nNodes) continue;
        float4 o0, o1;
        o0.x = acc[r][0] + bv[0]; o0.y = acc[r][1] + bv[1];
        o0.z = acc[r][2] + bv[2]; o0.w = acc[r][3] + bv[3];
        o1.x = acc[r][4] + bv[4]; o1.y = acc[r][5] + bv[5];
        o1.z = acc[r][6] + bv[6]; o1.w = acc[r][7] + bv[7];
        if (RELU) {
            o0.x = fmaxf(o0.x, 0.f); o0.y = fmaxf(o0.y, 0.f);
            o0.z = fmaxf(o0.z, 0.f); o0.w = fmaxf(o0.w, 0.f);
            o1.x = fmaxf(o1.x, 0.f); o1.y = fmaxf(o1.y, 0.f);
            o1.z = fmaxf(o1.z, 0.f); o1.w = fmaxf(o1.w, 0.f);
        }
        *(float4*)&hout[(size_t)n * 128 + ty * 4] = o0;
        *(float4*)&hout[(size_t)n * 128 + 64 + ty * 4] = o1;
    }
}

// ---------------- pooling ----------------
__global__ void cnt_kernel(const int* __restrict__ batch, int N, int* __restrict__ cnt) {
    int i = blockIdx.x * blockDim.x + threadIdx.x;
    if (i < N) atomicAdd(&cnt[batch[i]], 1);
}

__global__ void pool_kernel(const float* __restrict__ h, const int* __restrict__ batch,
                            float* __restrict__ pool, int nNodes) {
    int f = threadIdx.x & 127;
    int sub = threadIdx.x >> 7;
    int startn = blockIdx.x * 128;
    int endn = min(startn + 128, nNodes);
    float local = 0.f;
    int cur = -1;
    for (int n = startn + sub; n < endn; n += 2) {
        int g = batch[n];
        if (g != cur) {
            if (cur >= 0) atomicAdd(&pool[cur * 128 + f], local);
            cur = g; local = 0.f;
        }
        local += h[n * 128 + f];
    }
    if (cur >= 0) atomicAdd(&pool[cur * 128 + f], local);
}

__global__ void final_kernel(const float* __restrict__ pool, const int* __restrict__ cnt,
                             const float* __restrict__ Wlin, const float* __restrict__ blin,
                             float* __restrict__ out) {
    int idx = blockIdx.x * blockDim.x + threadIdx.x;   // 2048 = 128 graphs x 16 classes
    int g = idx >> 4, c = idx & 15;
    float s = 0.f;
    for (int k = 0; k < 128; ++k) s += pool[g * 128 + k] * Wlin[c * 128 + k];
    float inv = 1.0f / fmaxf((float)cnt[g], 1.0f);
    out[idx] = s * inv + blin[c];
}

// ---------------- launch ----------------
extern "C" void kernel_launch(void* const* d_in, const int* in_sizes, int n_in,
                              void* d_out, int out_size, void* d_ws, size_t ws_size,
                              hipStream_t stream) {
    const float* x      = (const float*)d_in[0];
    const int*   ei     = (const int*)d_in[1];
    const int*   batch  = (const int*)d_in[2];
    const float* W1_rel = (const float*)d_in[3];
    const float* b1     = (const float*)d_in[4];
    const float* W1_root= (const float*)d_in[5];
    const float* W2_rel = (const float*)d_in[6];
    const float* b2     = (const float*)d_in[7];
    const float* W2_root= (const float*)d_in[8];
    const float* W3_rel = (const float*)d_in[9];
    const float* b3     = (const float*)d_in[10];
    const float* W3_root= (const float*)d_in[11];
    const float* W_lin  = (const float*)d_in[12];
    const float* b_lin  = (const float*)d_in[13];
    float* out = (float*)d_out;

    const int N = in_sizes[2];          // 100000
    const int E = in_sizes[1] / 2;      // 1600000
    const int nb = (N + 511) / 512;

    // workspace carve-up (256B aligned)
    char* base = (char*)d_ws;
    size_t off = 0;
    auto carve = [&](size_t bytes) -> void* {
        void* p = base + off;
        off = (off + bytes + 255) & ~(size_t)255;
        return p;
    };
    int*   deg    = (int*)carve((size_t)N * 4);
    int*   tmp    = (int*)carve((size_t)N * 4);
    int*   bsum   = (int*)carve(1024);
    int*   rowp   = (int*)carve((size_t)(N + 1) * 4);
    int*   cursor = (int*)carve((size_t)N * 4);
    int*   csr    = (int*)carve((size_t)E * 4);
    float* aggbuf = (float*)carve((size_t)N * 128 * 4);
    float* hA     = (float*)carve((size_t)N * 128 * 4);
    float* hB     = (float*)carve((size_t)N * 128 * 4);
    float* pool   = (float*)carve((size_t)N_GRAPHS_C * 128 * 4);
    int*   gcnt   = (int*)carve((size_t)N_GRAPHS_C * 4);
    (void)ws_size;

    hipMemsetAsync(deg, 0, (size_t)N * 4, stream);
    hipMemsetAsync(cursor, 0, (size_t)N * 4, stream);
    hipMemsetAsync(pool, 0, (size_t)N_GRAPHS_C * 128 * 4, stream);
    hipMemsetAsync(gcnt, 0, (size_t)N_GRAPHS_C * 4, stream);

    // CSR build
    hist_kernel<<<(E + 255) / 256, 256, 0, stream>>>(ei, E, deg);
    scan1_kernel<<<nb, 512, 0, stream>>>(deg, N, tmp, bsum);
    scan2_kernel<<<1, 64, 0, stream>>>(bsum, nb);
    scan3_kernel<<<nb, 512, 0, stream>>>(tmp, bsum, N, rowp);
    fill_kernel<<<(E + 255) / 256, 256, 0, stream>>>(ei, E, rowp, cursor, csr);

    const int aggGrid = (N + 3) / 4;         // 4 waves/block, wave per node
    const int xGrid = (N + 127) / 128;

    // layer 1 (K = 64+64)
    agg_kernel<64><<<aggGrid, 256, 0, stream>>>(x, rowp, deg, csr, aggbuf, N);
    xform_kernel<128, true><<<xGrid, 256, 0, stream>>>(
        aggbuf, x, W1_rel, W1_root, b1, hA, N);

    // layer 2 (K = 128+128)
    agg_kernel<128><<<aggGrid, 256, 0, stream>>>(hA, rowp, deg, csr, aggbuf, N);
    xform_kernel<256, true><<<xGrid, 256, 0, stream>>>(
        aggbuf, hA, W2_rel, W2_root, b2, hB, N);

    // layer 3 (K = 128+128, no relu)
    agg_kernel<128><<<aggGrid, 256, 0, stream>>>(hB, rowp, deg, csr, aggbuf, N);
    xform_kernel<256, false><<<xGrid, 256, 0, stream>>>(
        aggbuf, hB, W3_rel, W3_root, b3, hA, N);

    // pooling + classifier
    cnt_kernel<<<(N + 255) / 256, 256, 0, stream>>>(batch, N, gcnt);
    pool_kernel<<<(N + 127) / 128, 256, 0, stream>>>(hA, batch, pool, N);
    final_kernel<<<8, 256, 0, stream>>>(pool, gcnt, W_lin, b_lin, out);
}

// Round 3
// 1007.288 us; speedup vs baseline: 1.9397x; 1.2151x over previous
//
#include <hip/hip_runtime.h>

#define N_NODES_C 100000
#define N_GRAPHS_C 128

// ---------------- CSR build ----------------
__global__ void hist_kernel(const int* __restrict__ ei, int E, int* __restrict__ deg) {
    int i = blockIdx.x * blockDim.x + threadIdx.x;
    if (i < E) atomicAdd(&deg[ei[E + i]], 1);   // dst row of edge_index
}

__global__ void scan1_kernel(const int* __restrict__ deg, int N,
                             int* __restrict__ tmp, int* __restrict__ bsum) {
    __shared__ int sh[512];
    int t = threadIdx.x;
    int i = blockIdx.x * 512 + t;
    int v = (i < N) ? deg[i] : 0;
    sh[t] = v;
    __syncthreads();
    for (int off = 1; off < 512; off <<= 1) {
        int add = (t >= off) ? sh[t - off] : 0;
        __syncthreads();
        sh[t] += add;
        __syncthreads();
    }
    if (i < N) tmp[i] = sh[t] - v;          // exclusive within block
    if (t == 511) bsum[blockIdx.x] = sh[511];
}

__global__ void scan2_kernel(int* bsum, int nb) {
    if (threadIdx.x == 0 && blockIdx.x == 0) {
        int run = 0;
        for (int j = 0; j < nb; ++j) { int v = bsum[j]; bsum[j] = run; run += v; }
    }
}

__global__ void scan3_kernel(const int* __restrict__ tmp, const int* __restrict__ bsum,
                             int N, int* __restrict__ rowp) {
    int i = blockIdx.x * 512 + threadIdx.x;
    if (i < N) rowp[i] = tmp[i] + bsum[blockIdx.x];
}

__global__ void fill_kernel(const int* __restrict__ ei, int E, const int* __restrict__ rowp,
                            int* __restrict__ cursor, int* __restrict__ csr) {
    int i = blockIdx.x * blockDim.x + threadIdx.x;
    if (i < E) {
        int d = ei[E + i];
        int pos = rowp[d] + atomicAdd(&cursor[d], 1);
        csr[pos] = ei[i];                    // src row
    }
}

// ---------------- neighbor aggregation (gather, wave per node) ----------------
template <int FIN>
__global__ __launch_bounds__(256) void agg_kernel(const float* __restrict__ xin,
                                                  const int* __restrict__ rowp,
                                                  const int* __restrict__ degv,
                                                  const int* __restrict__ csrc,
                                                  float* __restrict__ aggout, int nNodes) {
    int wave = blockIdx.x * (blockDim.x >> 6) + (threadIdx.x >> 6);
    int lane = threadIdx.x & 63;
    if (wave >= nNodes) return;
    int n = wave;
    int start = rowp[n];
    int deg = degv[n];
    float accx = 0.f, accy = 0.f;
    for (int base = 0; base < deg; base += 64) {
        int cnt = min(64, deg - base);
        int sid = (lane < cnt) ? csrc[start + base + lane] : 0;
        for (int j = 0; j < cnt; ++j) {
            int s = __shfl(sid, j);
            if (FIN == 64) {
                accx += xin[s * 64 + lane];
            } else {
                float2 v = ((const float2*)xin)[s * 64 + lane];
                accx += v.x; accy += v.y;
            }
        }
    }
    if (FIN == 64) {
        aggout[n * 64 + lane] = accx;
    } else {
        float2 o; o.x = accx; o.y = accy;
        ((float2*)aggout)[n * 64 + lane] = o;
    }
}

// ---------------- fused dual-GEMM transform (register-tiled) ----------------
// C[N x 128] = [agg | x] (N x KTOT) * [Wrel ; Wroot]^T (KTOT x 128) + bias, opt. ReLU
// block: 256 thr, tile 128 nodes x 128 outs; thread: 8 nodes x 8 outs register tile.
// LDS: sA[16][128] (k-major, transposed A chunk), sW[16][128]. 16 KB total.
template <int KTOT, bool RELU>
__global__ __launch_bounds__(256) void xform_kernel(
    const float* __restrict__ agg, const float* __restrict__ xin,
    const float* __restrict__ Wrel, const float* __restrict__ Wroot,
    const float* __restrict__ bias, float* __restrict__ hout, int nNodes)
{
    constexpr int KH = KTOT / 2;           // per-matrix K (64 or 128)
    __shared__ float sA[16][128];
    __shared__ float sW[16][128];
    const int t  = threadIdx.x;
    const int nb0 = blockIdx.x * 128;
    const int tx = t & 15;                 // node group: nodes tx*4..+3 and 64+tx*4..+3
    const int ty = t >> 4;                 // out group:  outs  ty*4..+3 and 64+ty*4..+3
    const int ln = t & 127;                // staging lane: node/out index within tile
    const int lj = t >> 7;                 // staging: which float4-column (0/1; +2 for 2nd)

    float acc[8][8];
#pragma unroll
    for (int r = 0; r < 8; ++r)
#pragma unroll
        for (int c = 0; c < 8; ++c) acc[r][c] = 0.f;

    const int gn = nb0 + ln;
    const bool gvalid = gn < nNodes;
    const size_t arow = (size_t)gn * KH;

    float4 va[2], vw[2];
    // prefetch chunk 0
    {
        const float* srcA = agg; const float* srcW = Wrel;
#pragma unroll
        for (int q = 0; q < 2; ++q) {
            int j = lj + q * 2;
            va[q] = gvalid ? *(const float4*)&srcA[arow + j * 4]
                           : make_float4(0.f, 0.f, 0.f, 0.f);
            vw[q] = *(const float4*)&srcW[(size_t)ln * KH + j * 4];
        }
    }

    constexpr int NC = KTOT / 16;          // chunks
#pragma unroll 1
    for (int cix = 0; cix < NC; ++cix) {
        __syncthreads();                   // previous chunk fully consumed
#pragma unroll
        for (int q = 0; q < 2; ++q) {
            int j = lj + q * 2;
            sA[j * 4 + 0][ln] = va[q].x; sA[j * 4 + 1][ln] = va[q].y;
            sA[j * 4 + 2][ln] = va[q].z; sA[j * 4 + 3][ln] = va[q].w;
            sW[j * 4 + 0][ln] = vw[q].x; sW[j * 4 + 1][ln] = vw[q].y;
            sW[j * 4 + 2][ln] = vw[q].z; sW[j * 4 + 3][ln] = vw[q].w;
        }
        __syncthreads();

        // prefetch next chunk while computing this one
        if (cix + 1 < NC) {
            int kc = (cix + 1) * 16;
            const float* srcA = (kc < KH) ? agg : xin;
            const float* srcW = (kc < KH) ? Wrel : Wroot;
            int kof = (kc < KH) ? kc : kc - KH;
#pragma unroll
            for (int q = 0; q < 2; ++q) {
                int j = lj + q * 2;
                va[q] = gvalid ? *(const float4*)&srcA[arow + kof + j * 4]
                               : make_float4(0.f, 0.f, 0.f, 0.f);
                vw[q] = *(const float4*)&srcW[(size_t)ln * KH + kof + j * 4];
            }
        }

#pragma unroll
        for (int i = 0; i < 16; ++i) {
            float4 a0 = *(const float4*)&sA[i][tx * 4];
            float4 a1 = *(const float4*)&sA[i][64 + tx * 4];
            float4 w0 = *(const float4*)&sW[i][ty * 4];
            float4 w1 = *(const float4*)&sW[i][64 + ty * 4];
            float av[8] = {a0.x, a0.y, a0.z, a0.w, a1.x, a1.y, a1.z, a1.w};
            float wv[8] = {w0.x, w0.y, w0.z, w0.w, w1.x, w1.y, w1.z, w1.w};
#pragma unroll
            for (int r = 0; r < 8; ++r)
#pragma unroll
                for (int c = 0; c < 8; ++c)
                    acc[r][c] += av[r] * wv[c];
        }
    }

    // epilogue
    float4 b0 = *(const float4*)&bias[ty * 4];
    float4 b1 = *(const float4*)&bias[64 + ty * 4];
    float bv[8] = {b0.x, b0.y, b0.z, b0.w, b1.x, b1.y, b1.z, b1.w};
#pragma unroll
    for (int r = 0; r < 8; ++r) {
        int n = nb0 + ((r < 4) ? (tx * 4 + r) : (64 + tx * 4 + (r - 4)));
        if (n >= nNodes) continue;
        float4 o0, o1;
        o0.x = acc[r][0] + bv[0]; o0.y = acc[r][1] + bv[1];
        o0.z = acc[r][2] + bv[2]; o0.w = acc[r][3] + bv[3];
        o1.x = acc[r][4] + bv[4]; o1.y = acc[r][5] + bv[5];
        o1.z = acc[r][6] + bv[6]; o1.w = acc[r][7] + bv[7];
        if (RELU) {
            o0.x = fmaxf(o0.x, 0.f); o0.y = fmaxf(o0.y, 0.f);
            o0.z = fmaxf(o0.z, 0.f); o0.w = fmaxf(o0.w, 0.f);
            o1.x = fmaxf(o1.x, 0.f); o1.y = fmaxf(o1.y, 0.f);
            o1.z = fmaxf(o1.z, 0.f); o1.w = fmaxf(o1.w, 0.f);
        }
        *(float4*)&hout[(size_t)n * 128 + ty * 4] = o0;
        *(float4*)&hout[(size_t)n * 128 + 64 + ty * 4] = o1;
    }
}

// ---------------- pooling (batch is SORTED: geometry, no atomics) ----------------
// gstart[g] = first node index with batch[i] >= g; gstart[128] = N.
__global__ void bounds_kernel(const int* __restrict__ batch, int N, int* __restrict__ gstart) {
    int g = blockIdx.x * blockDim.x + threadIdx.x;
    if (g > N_GRAPHS_C) return;
    int lo = 0, hi = N;
    while (lo < hi) {
        int mid = (lo + hi) >> 1;
        if (batch[mid] < g) lo = mid + 1; else hi = mid;
    }
    gstart[g] = lo;
}

// one block per graph; 256 threads = 2 node-subsets x 128 features
__global__ __launch_bounds__(256) void pool2_kernel(const float* __restrict__ h,
                                                    const int* __restrict__ gstart,
                                                    float* __restrict__ pooled) {
    int g = blockIdx.x;
    int f = threadIdx.x & 127;
    int sub = threadIdx.x >> 7;
    int s = gstart[g], e = gstart[g + 1];
    float acc = 0.f;
    for (int n = s + sub; n < e; n += 2) acc += h[(size_t)n * 128 + f];
    __shared__ float sh[128];
    if (sub == 1) sh[f] = acc;
    __syncthreads();
    if (sub == 0) {
        float tot = acc + sh[f];
        float inv = 1.0f / fmaxf((float)(e - s), 1.0f);
        pooled[g * 128 + f] = tot * inv;
    }
}

__global__ void final_kernel(const float* __restrict__ pooled,
                             const float* __restrict__ Wlin, const float* __restrict__ blin,
                             float* __restrict__ out) {
    int idx = blockIdx.x * blockDim.x + threadIdx.x;   // 2048 = 128 graphs x 16 classes
    int g = idx >> 4, c = idx & 15;
    float s = 0.f;
    for (int k = 0; k < 128; ++k) s += pooled[g * 128 + k] * Wlin[c * 128 + k];
    out[idx] = s + blin[c];
}

// ---------------- launch ----------------
extern "C" void kernel_launch(void* const* d_in, const int* in_sizes, int n_in,
                              void* d_out, int out_size, void* d_ws, size_t ws_size,
                              hipStream_t stream) {
    const float* x      = (const float*)d_in[0];
    const int*   ei     = (const int*)d_in[1];
    const int*   batch  = (const int*)d_in[2];
    const float* W1_rel = (const float*)d_in[3];
    const float* b1     = (const float*)d_in[4];
    const float* W1_root= (const float*)d_in[5];
    const float* W2_rel = (const float*)d_in[6];
    const float* b2     = (const float*)d_in[7];
    const float* W2_root= (const float*)d_in[8];
    const float* W3_rel = (const float*)d_in[9];
    const float* b3     = (const float*)d_in[10];
    const float* W3_root= (const float*)d_in[11];
    const float* W_lin  = (const float*)d_in[12];
    const float* b_lin  = (const float*)d_in[13];
    float* out = (float*)d_out;

    const int N = in_sizes[2];          // 100000
    const int E = in_sizes[1] / 2;      // 1600000
    const int nb = (N + 511) / 512;

    // workspace carve-up (256B aligned)
    char* base = (char*)d_ws;
    size_t off = 0;
    auto carve = [&](size_t bytes) -> void* {
        void* p = base + off;
        off = (off + bytes + 255) & ~(size_t)255;
        return p;
    };
    int*   deg    = (int*)carve((size_t)N * 4);
    int*   tmp    = (int*)carve((size_t)N * 4);
    int*   bsum   = (int*)carve(1024);
    int*   rowp   = (int*)carve((size_t)(N + 1) * 4);
    int*   cursor = (int*)carve((size_t)N * 4);
    int*   csr    = (int*)carve((size_t)E * 4);
    float* aggbuf = (float*)carve((size_t)N * 128 * 4);
    float* hA     = (float*)carve((size_t)N * 128 * 4);
    float* hB     = (float*)carve((size_t)N * 128 * 4);
    float* pooled = (float*)carve((size_t)N_GRAPHS_C * 128 * 4);
    int*   gstart = (int*)carve((size_t)(N_GRAPHS_C + 1) * 4);
    (void)ws_size;

    hipMemsetAsync(deg, 0, (size_t)N * 4, stream);
    hipMemsetAsync(cursor, 0, (size_t)N * 4, stream);

    // CSR build
    hist_kernel<<<(E + 255) / 256, 256, 0, stream>>>(ei, E, deg);
    scan1_kernel<<<nb, 512, 0, stream>>>(deg, N, tmp, bsum);
    scan2_kernel<<<1, 64, 0, stream>>>(bsum, nb);
    scan3_kernel<<<nb, 512, 0, stream>>>(tmp, bsum, N, rowp);
    fill_kernel<<<(E + 255) / 256, 256, 0, stream>>>(ei, E, rowp, cursor, csr);

    // graph boundaries (batch sorted) — overlaps CSR build work
    bounds_kernel<<<1, 192, 0, stream>>>(batch, N, gstart);

    const int aggGrid = (N + 3) / 4;         // 4 waves/block, wave per node
    const int xGrid = (N + 127) / 128;

    // layer 1 (K = 64+64)
    agg_kernel<64><<<aggGrid, 256, 0, stream>>>(x, rowp, deg, csr, aggbuf, N);
    xform_kernel<128, true><<<xGrid, 256, 0, stream>>>(
        aggbuf, x, W1_rel, W1_root, b1, hA, N);

    // layer 2 (K = 128+128)
    agg_kernel<128><<<aggGrid, 256, 0, stream>>>(hA, rowp, deg, csr, aggbuf, N);
    xform_kernel<256, true><<<xGrid, 256, 0, stream>>>(
        aggbuf, hA, W2_rel, W2_root, b2, hB, N);

    // layer 3 (K = 128+128, no relu)
    agg_kernel<128><<<aggGrid, 256, 0, stream>>>(hB, rowp, deg, csr, aggbuf, N);
    xform_kernel<256, false><<<xGrid, 256, 0, stream>>>(
        aggbuf, hB, W3_rel, W3_root, b3, hA, N);

    // pooling + classifier (no atomics)
    pool2_kernel<<<N_GRAPHS_C, 256, 0, stream>>>(hA, gstart, pooled);
    final_kernel<<<8, 256, 0, stream>>>(pooled, W_lin, b_lin, out);
}

// Round 4
// 910.704 us; speedup vs baseline: 2.1454x; 1.1061x over previous
//
#include <hip/hip_runtime.h>

#define N_NODES_C 100000
#define N_GRAPHS_C 128

// ---------------- CSR build ----------------
__global__ void hist_kernel(const int* __restrict__ ei, int E, int* __restrict__ deg) {
    int i = blockIdx.x * blockDim.x + threadIdx.x;
    if (i < E) atomicAdd(&deg[ei[E + i]], 1);   // dst row of edge_index
}

__global__ void scan1_kernel(const int* __restrict__ deg, int N,
                             int* __restrict__ tmp, int* __restrict__ bsum) {
    __shared__ int sh[512];
    int t = threadIdx.x;
    int i = blockIdx.x * 512 + t;
    int v = (i < N) ? deg[i] : 0;
    sh[t] = v;
    __syncthreads();
    for (int off = 1; off < 512; off <<= 1) {
        int add = (t >= off) ? sh[t - off] : 0;
        __syncthreads();
        sh[t] += add;
        __syncthreads();
    }
    if (i < N) tmp[i] = sh[t] - v;          // exclusive within block
    if (t == 511) bsum[blockIdx.x] = sh[511];
}

__global__ void scan2_kernel(int* bsum, int nb) {
    if (threadIdx.x == 0 && blockIdx.x == 0) {
        int run = 0;
        for (int j = 0; j < nb; ++j) { int v = bsum[j]; bsum[j] = run; run += v; }
    }
}

__global__ void scan3_kernel(const int* __restrict__ tmp, const int* __restrict__ bsum,
                             int N, int* __restrict__ rowp) {
    int i = blockIdx.x * 512 + threadIdx.x;
    if (i < N) rowp[i] = tmp[i] + bsum[blockIdx.x];
}

__global__ void fill_kernel(const int* __restrict__ ei, int E, const int* __restrict__ rowp,
                            int* __restrict__ cursor, int* __restrict__ csr) {
    int i = blockIdx.x * blockDim.x + threadIdx.x;
    if (i < E) {
        int d = ei[E + i];
        int pos = rowp[d] + atomicAdd(&cursor[d], 1);
        csr[pos] = ei[i];                    // src row
    }
}

// ---------------- neighbor aggregation (gather, wave per node, 4-way ILP) ----------------
template <int FIN>
__global__ __launch_bounds__(256) void agg_kernel(const float* __restrict__ xin,
                                                  const int* __restrict__ rowp,
                                                  const int* __restrict__ degv,
                                                  const int* __restrict__ csrc,
                                                  float* __restrict__ aggout, int nNodes) {
    int wave = blockIdx.x * 4 + (threadIdx.x >> 6);
    int lane = threadIdx.x & 63;
    if (wave >= nNodes) return;
    int start = rowp[wave];
    int deg = degv[wave];

    float s0 = 0.f, s1 = 0.f, s2 = 0.f, s3 = 0.f;                       // FIN==64
    float2 a0 = {0.f,0.f}, a1 = {0.f,0.f}, a2 = {0.f,0.f}, a3 = {0.f,0.f}; // FIN==128
    const float2* xin2 = (const float2*)xin;

    for (int base = 0; base < deg; base += 64) {
        int cnt = min(64, deg - base);
        int sid = (lane < cnt) ? csrc[start + base + lane] : 0;
        int j = 0;
        for (; j + 4 <= cnt; j += 4) {
            int n0 = __shfl(sid, j + 0);
            int n1 = __shfl(sid, j + 1);
            int n2 = __shfl(sid, j + 2);
            int n3 = __shfl(sid, j + 3);
            if (FIN == 64) {
                float v0 = xin[n0 * 64 + lane];
                float v1 = xin[n1 * 64 + lane];
                float v2 = xin[n2 * 64 + lane];
                float v3 = xin[n3 * 64 + lane];
                s0 += v0; s1 += v1; s2 += v2; s3 += v3;
            } else {
                float2 v0 = xin2[n0 * 64 + lane];
                float2 v1 = xin2[n1 * 64 + lane];
                float2 v2 = xin2[n2 * 64 + lane];
                float2 v3 = xin2[n3 * 64 + lane];
                a0.x += v0.x; a0.y += v0.y;
                a1.x += v1.x; a1.y += v1.y;
                a2.x += v2.x; a2.y += v2.y;
                a3.x += v3.x; a3.y += v3.y;
            }
        }
        for (; j < cnt; ++j) {
            int s = __shfl(sid, j);
            if (FIN == 64) {
                s0 += xin[s * 64 + lane];
            } else {
                float2 v = xin2[s * 64 + lane];
                a0.x += v.x; a0.y += v.y;
            }
        }
    }
    if (FIN == 64) {
        aggout[wave * 64 + lane] = (s0 + s1) + (s2 + s3);
    } else {
        float2 o;
        o.x = (a0.x + a1.x) + (a2.x + a3.x);
        o.y = (a0.y + a1.y) + (a2.y + a3.y);
        ((float2*)aggout)[wave * 64 + lane] = o;
    }
}

// ---------------- fused dual-GEMM transform (register-tiled, dbuf LDS) ----------------
// C[N x 128] = [agg | x] (N x KTOT) * [Wrel ; Wroot]^T (KTOT x 128) + bias, opt. ReLU
// block: 256 thr, tile 128 nodes x 128 outs; thread: 8 nodes x 8 outs register tile.
// LDS: double-buffered sA/sW [2][16][128] = 32 KB; ONE barrier per K-chunk.
template <int KTOT, bool RELU>
__global__ __launch_bounds__(256) void xform_kernel(
    const float* __restrict__ agg, const float* __restrict__ xin,
    const float* __restrict__ Wrel, const float* __restrict__ Wroot,
    const float* __restrict__ bias, float* __restrict__ hout, int nNodes)
{
    constexpr int KH = KTOT / 2;           // per-matrix K (64 or 128)
    constexpr int NC = KTOT / 16;          // chunks
    __shared__ float sA[2][16][128];
    __shared__ float sW[2][16][128];
    const int t  = threadIdx.x;
    const int nb0 = blockIdx.x * 128;
    const int tx = t & 15;                 // node group
    const int ty = t >> 4;                 // out group
    const int ln = t & 127;                // staging lane
    const int lj = t >> 7;                 // staging float4-column (0/1)

    float acc[8][8];
#pragma unroll
    for (int r = 0; r < 8; ++r)
#pragma unroll
        for (int c = 0; c < 8; ++c) acc[r][c] = 0.f;

    const int gn = nb0 + ln;
    const bool gvalid = gn < nNodes;
    const size_t arow = (size_t)gn * KH;

    float4 va[2], vw[2];
    auto loadChunk = [&](int cix) {
        int kc = cix * 16;
        const float* srcA = (kc < KH) ? agg : xin;
        const float* srcW = (kc < KH) ? Wrel : Wroot;
        int kof = (kc < KH) ? kc : kc - KH;
#pragma unroll
        for (int q = 0; q < 2; ++q) {
            int j = lj + q * 2;
            va[q] = gvalid ? *(const float4*)&srcA[arow + kof + j * 4]
                           : make_float4(0.f, 0.f, 0.f, 0.f);
            vw[q] = *(const float4*)&srcW[(size_t)ln * KH + kof + j * 4];
        }
    };
    auto writeChunk = [&](int buf) {
#pragma unroll
        for (int q = 0; q < 2; ++q) {
            int j = lj + q * 2;
            sA[buf][j * 4 + 0][ln] = va[q].x; sA[buf][j * 4 + 1][ln] = va[q].y;
            sA[buf][j * 4 + 2][ln] = va[q].z; sA[buf][j * 4 + 3][ln] = va[q].w;
            sW[buf][j * 4 + 0][ln] = vw[q].x; sW[buf][j * 4 + 1][ln] = vw[q].y;
            sW[buf][j * 4 + 2][ln] = vw[q].z; sW[buf][j * 4 + 3][ln] = vw[q].w;
        }
    };

    // prologue: chunk0 -> buf0; chunk1 loaded to regs
    loadChunk(0);
    writeChunk(0);
    if (NC > 1) loadChunk(1);
    __syncthreads();

#pragma unroll 1
    for (int cix = 0; cix < NC; ++cix) {
        const int cur = cix & 1;
        if (cix + 1 < NC) {
            writeChunk(cur ^ 1);           // safe: buf[cur^1] reads fenced by prev barrier
            if (cix + 2 < NC) loadChunk(cix + 2);  // global loads in flight under compute
        }
#pragma unroll
        for (int i = 0; i < 16; ++i) {
            float4 a0 = *(const float4*)&sA[cur][i][tx * 4];
            float4 a1 = *(const float4*)&sA[cur][i][64 + tx * 4];
            float4 w0 = *(const float4*)&sW[cur][i][ty * 4];
            float4 w1 = *(const float4*)&sW[cur][i][64 + ty * 4];
            float av[8] = {a0.x, a0.y, a0.z, a0.w, a1.x, a1.y, a1.z, a1.w};
            float wv[8] = {w0.x, w0.y, w0.z, w0.w, w1.x, w1.y, w1.z, w1.w};
#pragma unroll
            for (int r = 0; r < 8; ++r)
#pragma unroll
                for (int c = 0; c < 8; ++c)
                    acc[r][c] += av[r] * wv[c];
        }
        __syncthreads();                   // single barrier per chunk
    }

    // epilogue
    float4 b0 = *(const float4*)&bias[ty * 4];
    float4 b1 = *(const float4*)&bias[64 + ty * 4];
    float bv[8] = {b0.x, b0.y, b0.z, b0.w, b1.x, b1.y, b1.z, b1.w};
#pragma unroll
    for (int r = 0; r < 8; ++r) {
        int n = nb0 + ((r < 4) ? (tx * 4 + r) : (64 + tx * 4 + (r - 4)));
        if (n >= nNodes) continue;
        float4 o0, o1;
        o0.x = acc[r][0] + bv[0]; o0.y = acc[r][1] + bv[1];
        o0.z = acc[r][2] + bv[2]; o0.w = acc[r][3] + bv[3];
        o1.x = acc[r][4] + bv[4]; o1.y = acc[r][5] + bv[5];
        o1.z = acc[r][6] + bv[6]; o1.w = acc[r][7] + bv[7];
        if (RELU) {
            o0.x = fmaxf(o0.x, 0.f); o0.y = fmaxf(o0.y, 0.f);
            o0.z = fmaxf(o0.z, 0.f); o0.w = fmaxf(o0.w, 0.f);
            o1.x = fmaxf(o1.x, 0.f); o1.y = fmaxf(o1.y, 0.f);
            o1.z = fmaxf(o1.z, 0.f); o1.w = fmaxf(o1.w, 0.f);
        }
        *(float4*)&hout[(size_t)n * 128 + ty * 4] = o0;
        *(float4*)&hout[(size_t)n * 128 + 64 + ty * 4] = o1;
    }
}

// ---------------- pooling (batch is SORTED: geometry, no atomics) ----------------
__global__ void bounds_kernel(const int* __restrict__ batch, int N, int* __restrict__ gstart) {
    int g = blockIdx.x * blockDim.x + threadIdx.x;
    if (g > N_GRAPHS_C) return;
    int lo = 0, hi = N;
    while (lo < hi) {
        int mid = (lo + hi) >> 1;
        if (batch[mid] < g) lo = mid + 1; else hi = mid;
    }
    gstart[g] = lo;
}

__global__ __launch_bounds__(256) void pool2_kernel(const float* __restrict__ h,
                                                    const int* __restrict__ gstart,
                                                    float* __restrict__ pooled) {
    int g = blockIdx.x;
    int f = threadIdx.x & 127;
    int sub = threadIdx.x >> 7;
    int s = gstart[g], e = gstart[g + 1];
    float acc = 0.f;
    for (int n = s + sub; n < e; n += 2) acc += h[(size_t)n * 128 + f];
    __shared__ float sh[128];
    if (sub == 1) sh[f] = acc;
    __syncthreads();
    if (sub == 0) {
        float tot = acc + sh[f];
        float inv = 1.0f / fmaxf((float)(e - s), 1.0f);
        pooled[g * 128 + f] = tot * inv;
    }
}

__global__ void final_kernel(const float* __restrict__ pooled,
                             const float* __restrict__ Wlin, const float* __restrict__ blin,
                             float* __restrict__ out) {
    int idx = blockIdx.x * blockDim.x + threadIdx.x;   // 2048 = 128 graphs x 16 classes
    int g = idx >> 4, c = idx & 15;
    float s = 0.f;
    for (int k = 0; k < 128; ++k) s += pooled[g * 128 + k] * Wlin[c * 128 + k];
    out[idx] = s + blin[c];
}

// ---------------- launch ----------------
extern "C" void kernel_launch(void* const* d_in, const int* in_sizes, int n_in,
                              void* d_out, int out_size, void* d_ws, size_t ws_size,
                              hipStream_t stream) {
    const float* x      = (const float*)d_in[0];
    const int*   ei     = (const int*)d_in[1];
    const int*   batch  = (const int*)d_in[2];
    const float* W1_rel = (const float*)d_in[3];
    const float* b1     = (const float*)d_in[4];
    const float* W1_root= (const float*)d_in[5];
    const float* W2_rel = (const float*)d_in[6];
    const float* b2     = (const float*)d_in[7];
    const float* W2_root= (const float*)d_in[8];
    const float* W3_rel = (const float*)d_in[9];
    const float* b3     = (const float*)d_in[10];
    const float* W3_root= (const float*)d_in[11];
    const float* W_lin  = (const float*)d_in[12];
    const float* b_lin  = (const float*)d_in[13];
    float* out = (float*)d_out;

    const int N = in_sizes[2];          // 100000
    const int E = in_sizes[1] / 2;      // 1600000
    const int nb = (N + 511) / 512;

    // workspace carve-up (256B aligned)
    char* base = (char*)d_ws;
    size_t off = 0;
    auto carve = [&](size_t bytes) -> void* {
        void* p = base + off;
        off = (off + bytes + 255) & ~(size_t)255;
        return p;
    };
    int*   deg    = (int*)carve((size_t)N * 4);
    int*   tmp    = (int*)carve((size_t)N * 4);
    int*   bsum   = (int*)carve(1024);
    int*   rowp   = (int*)carve((size_t)(N + 1) * 4);
    int*   cursor = (int*)carve((size_t)N * 4);
    int*   csr    = (int*)carve((size_t)E * 4);
    float* aggbuf = (float*)carve((size_t)N * 128 * 4);
    float* hA     = (float*)carve((size_t)N * 128 * 4);
    float* hB     = (float*)carve((size_t)N * 128 * 4);
    float* pooled = (float*)carve((size_t)N_GRAPHS_C * 128 * 4);
    int*   gstart = (int*)carve((size_t)(N_GRAPHS_C + 1) * 4);
    (void)ws_size;

    hipMemsetAsync(deg, 0, (size_t)N * 4, stream);
    hipMemsetAsync(cursor, 0, (size_t)N * 4, stream);

    // CSR build
    hist_kernel<<<(E + 255) / 256, 256, 0, stream>>>(ei, E, deg);
    scan1_kernel<<<nb, 512, 0, stream>>>(deg, N, tmp, bsum);
    scan2_kernel<<<1, 64, 0, stream>>>(bsum, nb);
    scan3_kernel<<<nb, 512, 0, stream>>>(tmp, bsum, N, rowp);
    fill_kernel<<<(E + 255) / 256, 256, 0, stream>>>(ei, E, rowp, cursor, csr);

    // graph boundaries (batch sorted)
    bounds_kernel<<<1, 192, 0, stream>>>(batch, N, gstart);

    const int aggGrid = (N + 3) / 4;         // 4 waves/block, wave per node
    const int xGrid = (N + 127) / 128;

    // layer 1 (K = 64+64)
    agg_kernel<64><<<aggGrid, 256, 0, stream>>>(x, rowp, deg, csr, aggbuf, N);
    xform_kernel<128, true><<<xGrid, 256, 0, stream>>>(
        aggbuf, x, W1_rel, W1_root, b1, hA, N);

    // layer 2 (K = 128+128)
    agg_kernel<128><<<aggGrid, 256, 0, stream>>>(hA, rowp, deg, csr, aggbuf, N);
    xform_kernel<256, true><<<xGrid, 256, 0, stream>>>(
        aggbuf, hA, W2_rel, W2_root, b2, hB, N);

    // layer 3 (K = 128+128, no relu)
    agg_kernel<128><<<aggGrid, 256, 0, stream>>>(hB, rowp, deg, csr, aggbuf, N);
    xform_kernel<256, false><<<xGrid, 256, 0, stream>>>(
        aggbuf, hB, W3_rel, W3_root, b3, hA, N);

    // pooling + classifier (no atomics)
    pool2_kernel<<<N_GRAPHS_C, 256, 0, stream>>>(hA, gstart, pooled);
    final_kernel<<<8, 256, 0, stream>>>(pooled, W_lin, b_lin, out);
}

// Round 5
// 827.267 us; speedup vs baseline: 2.3618x; 1.1009x over previous
//
#include <hip/hip_runtime.h>

#define N_NODES_C 100000
#define N_GRAPHS_C 128

typedef __attribute__((ext_vector_type(8))) __bf16 bf16x8;
typedef __attribute__((ext_vector_type(4))) float f32x4;

__device__ __forceinline__ f32x4 mfma16(bf16x8 a, bf16x8 b, f32x4 c) {
    return __builtin_amdgcn_mfma_f32_16x16x32_bf16(a, b, c, 0, 0, 0);
}

// ---------------- CSR build ----------------
__global__ void hist_kernel(const int* __restrict__ ei, int E, int* __restrict__ deg) {
    int i = blockIdx.x * blockDim.x + threadIdx.x;
    if (i < E) atomicAdd(&deg[ei[E + i]], 1);   // dst row of edge_index
}

__global__ void scan1_kernel(const int* __restrict__ deg, int N,
                             int* __restrict__ tmp, int* __restrict__ bsum) {
    __shared__ int sh[512];
    int t = threadIdx.x;
    int i = blockIdx.x * 512 + t;
    int v = (i < N) ? deg[i] : 0;
    sh[t] = v;
    __syncthreads();
    for (int off = 1; off < 512; off <<= 1) {
        int add = (t >= off) ? sh[t - off] : 0;
        __syncthreads();
        sh[t] += add;
        __syncthreads();
    }
    if (i < N) tmp[i] = sh[t] - v;
    if (t == 511) bsum[blockIdx.x] = sh[511];
}

__global__ void scan2_kernel(int* bsum, int nb) {
    if (threadIdx.x == 0 && blockIdx.x == 0) {
        int run = 0;
        for (int j = 0; j < nb; ++j) { int v = bsum[j]; bsum[j] = run; run += v; }
    }
}

__global__ void scan3_kernel(const int* __restrict__ tmp, const int* __restrict__ bsum,
                             int N, int* __restrict__ rowp) {
    int i = blockIdx.x * 512 + threadIdx.x;
    if (i < N) rowp[i] = tmp[i] + bsum[blockIdx.x];
}

__global__ void fill_kernel(const int* __restrict__ ei, int E, const int* __restrict__ rowp,
                            int* __restrict__ cursor, int* __restrict__ csr) {
    int i = blockIdx.x * blockDim.x + threadIdx.x;
    if (i < E) {
        int d = ei[E + i];
        int pos = rowp[d] + atomicAdd(&cursor[d], 1);
        csr[pos] = ei[i];
    }
}

// ---------------- neighbor aggregation (gather, wave per node, 8-way ILP) ----------------
template <int FIN>
__global__ __launch_bounds__(256) void agg_kernel(const float* __restrict__ xin,
                                                  const int* __restrict__ rowp,
                                                  const int* __restrict__ degv,
                                                  const int* __restrict__ csrc,
                                                  float* __restrict__ aggout, int nNodes) {
    int wave = blockIdx.x * 4 + (threadIdx.x >> 6);
    int lane = threadIdx.x & 63;
    if (wave >= nNodes) return;
    int start = rowp[wave];
    int deg = degv[wave];
    const float2* xin2 = (const float2*)xin;

    if (FIN == 64) {
        float s[8];
#pragma unroll
        for (int q = 0; q < 8; ++q) s[q] = 0.f;
        for (int base = 0; base < deg; base += 64) {
            int cnt = min(64, deg - base);
            int sid = (lane < cnt) ? csrc[start + base + lane] : 0;
            int j = 0;
            for (; j + 8 <= cnt; j += 8) {
                int n[8];
#pragma unroll
                for (int q = 0; q < 8; ++q) n[q] = __shfl(sid, j + q);
#pragma unroll
                for (int q = 0; q < 8; ++q) s[q] += xin[n[q] * 64 + lane];
            }
            for (; j < cnt; ++j) s[0] += xin[__shfl(sid, j) * 64 + lane];
        }
        aggout[wave * 64 + lane] = ((s[0]+s[1])+(s[2]+s[3])) + ((s[4]+s[5])+(s[6]+s[7]));
    } else {
        float2 a[8];
#pragma unroll
        for (int q = 0; q < 8; ++q) { a[q].x = 0.f; a[q].y = 0.f; }
        for (int base = 0; base < deg; base += 64) {
            int cnt = min(64, deg - base);
            int sid = (lane < cnt) ? csrc[start + base + lane] : 0;
            int j = 0;
            for (; j + 8 <= cnt; j += 8) {
                int n[8];
#pragma unroll
                for (int q = 0; q < 8; ++q) n[q] = __shfl(sid, j + q);
#pragma unroll
                for (int q = 0; q < 8; ++q) {
                    float2 v = xin2[n[q] * 64 + lane];
                    a[q].x += v.x; a[q].y += v.y;
                }
            }
            for (; j < cnt; ++j) {
                float2 v = xin2[__shfl(sid, j) * 64 + lane];
                a[0].x += v.x; a[0].y += v.y;
            }
        }
        float2 o;
        o.x = ((a[0].x+a[1].x)+(a[2].x+a[3].x)) + ((a[4].x+a[5].x)+(a[6].x+a[7].x));
        o.y = ((a[0].y+a[1].y)+(a[2].y+a[3].y)) + ((a[4].y+a[5].y)+(a[6].y+a[7].y));
        ((float2*)aggout)[wave * 64 + lane] = o;
    }
}

// ---------------- weight prep: split fp32 W -> bf16 hi/lo, pre-swizzled LDS image ----
// Image per 32-k chunk: 16 KB = [hi plane: 128 cols x 4 slots x 16B][lo plane: same].
// slot' = slot ^ ((col>>1)&3). Element pair (2k,2k+1) packed low/high in one uint.
__global__ void wprep_kernel(const float* __restrict__ Wrel, const float* __restrict__ Wroot,
                             int KH, unsigned* __restrict__ img) {
    int cid = blockIdx.x;          // chunk
    int col = threadIdx.x;         // 0..127 (output channel)
    int key = (col >> 1) & 3;
    unsigned hiw[16], low[16];
#pragma unroll 4
    for (int p = 0; p < 16; ++p) {
        int k0 = cid * 32 + p * 2;
        float v0 = (k0 < KH) ? Wrel[col * KH + k0] : Wroot[col * KH + k0 - KH];
        float v1 = (k0 + 1 < KH) ? Wrel[col * KH + k0 + 1] : Wroot[col * KH + k0 + 1 - KH];
        unsigned u0 = __float_as_uint(v0), u1 = __float_as_uint(v1);
        unsigned h0 = u0 & 0xFFFF0000u, h1 = u1 & 0xFFFF0000u;
        float l0 = v0 - __uint_as_float(h0), l1 = v1 - __uint_as_float(h1);
        unsigned lb0 = __float_as_uint(l0) & 0xFFFF0000u;
        unsigned lb1 = __float_as_uint(l1) & 0xFFFF0000u;
        hiw[p] = (h0 >> 16) | h1;
        low[p] = (lb0 >> 16) | lb1;
    }
    unsigned* cb = img + (size_t)cid * 4096;
#pragma unroll 4
    for (int p = 0; p < 16; ++p) {
        int s = p >> 2, w = p & 3;
        int sp = s ^ key;
        cb[col * 16 + sp * 4 + w] = hiw[p];
        cb[2048 + col * 16 + sp * 4 + w] = low[p];
    }
}

// ---------------- fused dual-GEMM transform via split-bf16 MFMA ----------------
// C[N x 128] = [agg | xin] (N x KTOT) * [Wrel;Wroot]^T + bias, opt ReLU.
// C = Ah*Wh + Ah*Wl + Al*Wh in mfma_f32_16x16x32_bf16, fp32 accum.
// Block: 256 thr (4 waves), tile 128 nodes x 128 outs, K chunked by 32, dbuf LDS 64 KB.
template <int KTOT, bool RELU>
__global__ __launch_bounds__(256, 2) void xform_kernel(
    const float* __restrict__ agg, const float* __restrict__ xin,
    const unsigned* __restrict__ wimg, const float* __restrict__ bias,
    float* __restrict__ hout, int nNodes)
{
    constexpr int KH = KTOT / 2;
    constexpr int NC = KTOT / 32;
    __shared__ unsigned sA[2][4096];   // [hi 2048 | lo 2048] uints; row stride 16 uints
    __shared__ unsigned sW[2][4096];
    const int t = threadIdx.x;
    const int nb0 = blockIdx.x * 128;

    // staging roles: 2 threads per node-row, 16 k each
    const int srow = t >> 1;
    const int skh = t & 1;
    const int skey = (srow >> 1) & 3;
    const int gn = nb0 + srow;
    const bool gvalid = gn < nNodes;
    const size_t arow = (size_t)gn * KH;

    float4 va[4]; uint4 vw[4];
    auto loadChunk = [&](int cix) {
        int kc = cix * 32 + skh * 16;
        const float* srcA = (kc < KH) ? agg : xin;
        int kof = (kc < KH) ? kc : kc - KH;
        if (gvalid) {
#pragma unroll
            for (int q = 0; q < 4; ++q)
                va[q] = *(const float4*)&srcA[arow + kof + q * 4];
        } else {
#pragma unroll
            for (int q = 0; q < 4; ++q) va[q] = make_float4(0.f, 0.f, 0.f, 0.f);
        }
        const uint4* wsrc = (const uint4*)(wimg + (size_t)cix * 4096) + t * 4;
#pragma unroll
        for (int q = 0; q < 4; ++q) vw[q] = wsrc[q];
    };
    auto writeChunk = [&](int buf) {
        // W: straight 64B copy (image is pre-swizzled)
        uint4* wd = (uint4*)&sW[buf][t * 16];
#pragma unroll
        for (int q = 0; q < 4; ++q) wd[q] = vw[q];
        // A: split fp32 -> bf16 hi/lo, pack pairs, swizzled slot writes
        unsigned hiw[8], low[8];
#pragma unroll
        for (int q = 0; q < 4; ++q) {
            float vv[4] = {va[q].x, va[q].y, va[q].z, va[q].w};
#pragma unroll
            for (int h = 0; h < 2; ++h) {
                unsigned u0 = __float_as_uint(vv[h * 2]), u1 = __float_as_uint(vv[h * 2 + 1]);
                unsigned h0 = u0 & 0xFFFF0000u, h1 = u1 & 0xFFFF0000u;
                float l0 = vv[h * 2] - __uint_as_float(h0);
                float l1 = vv[h * 2 + 1] - __uint_as_float(h1);
                unsigned lb0 = __float_as_uint(l0) & 0xFFFF0000u;
                unsigned lb1 = __float_as_uint(l1) & 0xFFFF0000u;
                hiw[q * 2 + h] = (h0 >> 16) | h1;
                low[q * 2 + h] = (lb0 >> 16) | lb1;
            }
        }
        int s0 = (skh * 2) ^ skey, s1 = (skh * 2 + 1) ^ skey;
        unsigned* abH = &sA[buf][srow * 16];
        unsigned* abL = &sA[buf][2048 + srow * 16];
        *(uint4*)&abH[s0 * 4] = make_uint4(hiw[0], hiw[1], hiw[2], hiw[3]);
        *(uint4*)&abH[s1 * 4] = make_uint4(hiw[4], hiw[5], hiw[6], hiw[7]);
        *(uint4*)&abL[s0 * 4] = make_uint4(low[0], low[1], low[2], low[3]);
        *(uint4*)&abL[s1 * 4] = make_uint4(low[4], low[5], low[6], low[7]);
    };

    // compute roles
    const int lane = t & 63, wv = t >> 6;
    const int r15 = lane & 15, hi4 = lane >> 4;
    const int ckey = (r15 >> 1) & 3;
    const int cslot = (hi4 ^ ckey) * 4;          // uint offset within a 16-uint row
    const int arow0 = (wv * 32 + r15) * 16;
    const int arow1 = arow0 + 256;               // +16 rows

    f32x4 acc[2][8];
#pragma unroll
    for (int g = 0; g < 2; ++g)
#pragma unroll
        for (int j = 0; j < 8; ++j) acc[g][j] = (f32x4){0.f, 0.f, 0.f, 0.f};

    float bj[8];
#pragma unroll
    for (int j = 0; j < 8; ++j) bj[j] = bias[j * 16 + r15];

    loadChunk(0);
    writeChunk(0);
    if (NC > 1) loadChunk(1);
    __syncthreads();

#pragma unroll 1
    for (int cix = 0; cix < NC; ++cix) {
        const int cur = cix & 1;
        if (cix + 1 < NC) {
            writeChunk(cur ^ 1);
            if (cix + 2 < NC) loadChunk(cix + 2);
        }
        const unsigned* A = sA[cur];
        const unsigned* W = sW[cur];
        bf16x8 ah0 = *(const bf16x8*)&A[arow0 + cslot];
        bf16x8 ah1 = *(const bf16x8*)&A[arow1 + cslot];
        bf16x8 al0 = *(const bf16x8*)&A[2048 + arow0 + cslot];
        bf16x8 al1 = *(const bf16x8*)&A[2048 + arow1 + cslot];
#pragma unroll
        for (int j = 0; j < 8; ++j) {
            int cb = (j * 16 + r15) * 16;
            bf16x8 bh = *(const bf16x8*)&W[cb + cslot];
            bf16x8 bl = *(const bf16x8*)&W[2048 + cb + cslot];
            acc[0][j] = mfma16(ah0, bh, acc[0][j]);
            acc[1][j] = mfma16(ah1, bh, acc[1][j]);
            acc[0][j] = mfma16(ah0, bl, acc[0][j]);
            acc[1][j] = mfma16(ah1, bl, acc[1][j]);
            acc[0][j] = mfma16(al0, bh, acc[0][j]);
            acc[1][j] = mfma16(al1, bh, acc[1][j]);
        }
        __syncthreads();
    }

    // epilogue: D col=lane&15, row=(lane>>4)*4+reg (m89-verified)
#pragma unroll
    for (int g2 = 0; g2 < 2; ++g2) {
#pragma unroll
        for (int r = 0; r < 4; ++r) {
            int node = nb0 + wv * 32 + g2 * 16 + hi4 * 4 + r;
            if (node >= nNodes) continue;
            float* orow = &hout[(size_t)node * 128];
#pragma unroll
            for (int j = 0; j < 8; ++j) {
                float v = acc[g2][j][r] + bj[j];
                if (RELU) v = fmaxf(v, 0.f);
                orow[j * 16 + r15] = v;
            }
        }
    }
}

// ---------------- pooling (batch is SORTED: geometry, no atomics) ----------------
__global__ void bounds_kernel(const int* __restrict__ batch, int N, int* __restrict__ gstart) {
    int g = blockIdx.x * blockDim.x + threadIdx.x;
    if (g > N_GRAPHS_C) return;
    int lo = 0, hi = N;
    while (lo < hi) {
        int mid = (lo + hi) >> 1;
        if (batch[mid] < g) lo = mid + 1; else hi = mid;
    }
    gstart[g] = lo;
}

__global__ __launch_bounds__(256) void pool2_kernel(const float* __restrict__ h,
                                                    const int* __restrict__ gstart,
                                                    float* __restrict__ pooled) {
    int g = blockIdx.x;
    int f = threadIdx.x & 127;
    int sub = threadIdx.x >> 7;
    int s = gstart[g], e = gstart[g + 1];
    float acc = 0.f;
    for (int n = s + sub; n < e; n += 2) acc += h[(size_t)n * 128 + f];
    __shared__ float sh[128];
    if (sub == 1) sh[f] = acc;
    __syncthreads();
    if (sub == 0) {
        float tot = acc + sh[f];
        float inv = 1.0f / fmaxf((float)(e - s), 1.0f);
        pooled[g * 128 + f] = tot * inv;
    }
}

__global__ void final_kernel(const float* __restrict__ pooled,
                             const float* __restrict__ Wlin, const float* __restrict__ blin,
                             float* __restrict__ out) {
    int idx = blockIdx.x * blockDim.x + threadIdx.x;   // 2048 = 128 x 16
    int g = idx >> 4, c = idx & 15;
    float s = 0.f;
    for (int k = 0; k < 128; ++k) s += pooled[g * 128 + k] * Wlin[c * 128 + k];
    out[idx] = s + blin[c];
}

// ---------------- launch ----------------
extern "C" void kernel_launch(void* const* d_in, const int* in_sizes, int n_in,
                              void* d_out, int out_size, void* d_ws, size_t ws_size,
                              hipStream_t stream) {
    const float* x      = (const float*)d_in[0];
    const int*   ei     = (const int*)d_in[1];
    const int*   batch  = (const int*)d_in[2];
    const float* W1_rel = (const float*)d_in[3];
    const float* b1     = (const float*)d_in[4];
    const float* W1_root= (const float*)d_in[5];
    const float* W2_rel = (const float*)d_in[6];
    const float* b2     = (const float*)d_in[7];
    const float* W2_root= (const float*)d_in[8];
    const float* W3_rel = (const float*)d_in[9];
    const float* b3     = (const float*)d_in[10];
    const float* W3_root= (const float*)d_in[11];
    const float* W_lin  = (const float*)d_in[12];
    const float* b_lin  = (const float*)d_in[13];
    float* out = (float*)d_out;

    const int N = in_sizes[2];          // 100000
    const int E = in_sizes[1] / 2;      // 1600000
    const int nb = (N + 511) / 512;

    char* base = (char*)d_ws;
    size_t off = 0;
    auto carve = [&](size_t bytes) -> void* {
        void* p = base + off;
        off = (off + bytes + 255) & ~(size_t)255;
        return p;
    };
    int*      deg    = (int*)carve((size_t)N * 4);
    int*      tmp    = (int*)carve((size_t)N * 4);
    int*      bsum   = (int*)carve(1024);
    int*      rowp   = (int*)carve((size_t)(N + 1) * 4);
    int*      cursor = (int*)carve((size_t)N * 4);
    int*      csr    = (int*)carve((size_t)E * 4);
    float*    aggbuf = (float*)carve((size_t)N * 128 * 4);
    float*    hA     = (float*)carve((size_t)N * 128 * 4);
    float*    hB     = (float*)carve((size_t)N * 128 * 4);
    float*    pooled = (float*)carve((size_t)N_GRAPHS_C * 128 * 4);
    int*      gstart = (int*)carve((size_t)(N_GRAPHS_C + 1) * 4);
    unsigned* wimg1  = (unsigned*)carve((size_t)4 * 4096 * 4);   // 64 KB
    unsigned* wimg2  = (unsigned*)carve((size_t)8 * 4096 * 4);   // 128 KB
    unsigned* wimg3  = (unsigned*)carve((size_t)8 * 4096 * 4);   // 128 KB
    (void)ws_size;

    hipMemsetAsync(deg, 0, (size_t)N * 4, stream);
    hipMemsetAsync(cursor, 0, (size_t)N * 4, stream);

    // weight prep (tiny)
    wprep_kernel<<<4, 128, 0, stream>>>(W1_rel, W1_root, 64, wimg1);
    wprep_kernel<<<8, 128, 0, stream>>>(W2_rel, W2_root, 128, wimg2);
    wprep_kernel<<<8, 128, 0, stream>>>(W3_rel, W3_root, 128, wimg3);

    // CSR build
    hist_kernel<<<(E + 255) / 256, 256, 0, stream>>>(ei, E, deg);
    scan1_kernel<<<nb, 512, 0, stream>>>(deg, N, tmp, bsum);
    scan2_kernel<<<1, 64, 0, stream>>>(bsum, nb);
    scan3_kernel<<<nb, 512, 0, stream>>>(tmp, bsum, N, rowp);
    fill_kernel<<<(E + 255) / 256, 256, 0, stream>>>(ei, E, rowp, cursor, csr);

    // graph boundaries (batch sorted)
    bounds_kernel<<<1, 192, 0, stream>>>(batch, N, gstart);

    const int aggGrid = (N + 3) / 4;     // 4 waves/block, wave per node
    const int xGrid = (N + 127) / 128;

    // layer 1 (K = 64+64)
    agg_kernel<64><<<aggGrid, 256, 0, stream>>>(x, rowp, deg, csr, aggbuf, N);
    xform_kernel<128, true><<<xGrid, 256, 0, stream>>>(aggbuf, x, wimg1, b1, hA, N);

    // layer 2 (K = 128+128)
    agg_kernel<128><<<aggGrid, 256, 0, stream>>>(hA, rowp, deg, csr, aggbuf, N);
    xform_kernel<256, true><<<xGrid, 256, 0, stream>>>(aggbuf, hA, wimg2, b2, hB, N);

    // layer 3 (K = 128+128, no relu)
    agg_kernel<128><<<aggGrid, 256, 0, stream>>>(hB, rowp, deg, csr, aggbuf, N);
    xform_kernel<256, false><<<xGrid, 256, 0, stream>>>(aggbuf, hB, wimg3, b3, hA, N);

    // pooling + classifier (no atomics)
    pool2_kernel<<<N_GRAPHS_C, 256, 0, stream>>>(hA, gstart, pooled);
    final_kernel<<<8, 256, 0, stream>>>(pooled, W_lin, b_lin, out);
}